// Round 8
// baseline (238.761 us; speedup 1.0000x reference)
//
#include <hip/hip_runtime.h>
#include <hip/hip_cooperative_groups.h>
#include <math.h>

namespace cg = cooperative_groups;

// HistDRDoubleConv on gfx950 — single cooperative kernel (grid 512), 4 phases /
// 3 grid.syncs, with a 4-kernel fallback if the coop launch is rejected.
// B=8, Cin=Cmid=Cout=8, H=W=256, R=8. Pool windows at rows/cols {0,85,170}, k=86.
//  P1 prep:   rowsum(x)->rs1 ; xh = fp16 channel-pair planes ; regmap = argmax(hist)
//  P2 conv1:  per-block inline buildK1(rs1) -> conv(xh)+BN/ReLU -> y1h (fp16 planes)
//  P3 rowsum: rowsum_h(y1h) -> rs2
//  P4 conv2:  inline buildK2(rs2) -> conv(y1h)+BN/ReLU -> out (f32)
// Conv: 4 px/thread, v_dot2_f32_f16 over ci-pairs; K in LDS, region stride
// 292 dwords so different-region lanes hit disjoint bank quads (conflict-free).
// ConvSmem is a single 12.9 KB block reused by both conv phases (residency).

#define HWPX 65536
#define HDIM 256

typedef __fp16 h2 __attribute__((ext_vector_type(2)));

#if defined(__has_builtin) && __has_builtin(__builtin_amdgcn_fdot2)
__device__ __forceinline__ float fdot2(h2 a, h2 b, float c) {
  return __builtin_amdgcn_fdot2(a, b, c, false);
}
#else
__device__ __forceinline__ float fdot2(h2 a, h2 b, float c) {
  return c + (float)a[0] * (float)b[0] + (float)a[1] * (float)b[1];
}
#endif

union UH { uint u; h2 h; };
union U4H { uint4 u4; h2 h[4]; };

struct ConvSmem {
  uint KsU[8 * 292];        // 9344 B
  float pp[72][3];
  float pP[8][9];
  float hh[576];
  float bns[8], bnsh[8];
};

// ---------------- P1 unit: rowsums + fp16 pair planes + regmap --------------
__device__ __forceinline__ void prep_unit(int u, int t,
                                          const float* __restrict__ x,
                                          const float* __restrict__ hist,
                                          float* __restrict__ rs1,
                                          uint* __restrict__ xh,
                                          unsigned char* __restrict__ regmap) {
  int wave = t >> 6, lane = t & 63;
  if (u < 2048) {
    int cp = u & 3, rg = (u >> 2) & 63, b = u >> 8;
    int row = rg * 4 + wave;
    const float* pa = x + ((size_t)(b * 8 + 2 * cp) * HWPX) + row * HDIM + lane * 4;
    const float4 va = *(const float4*)pa;
    const float4 vb = *(const float4*)(pa + HWPX);
    U4H pk;
    pk.h[0] = __builtin_amdgcn_cvt_pkrtz(va.x, vb.x);
    pk.h[1] = __builtin_amdgcn_cvt_pkrtz(va.y, vb.y);
    pk.h[2] = __builtin_amdgcn_cvt_pkrtz(va.z, vb.z);
    pk.h[3] = __builtin_amdgcn_cvt_pkrtz(va.w, vb.w);
    *(uint4*)(xh + (size_t)(b * 4 + cp) * HWPX + row * HDIM + lane * 4) = pk.u4;
    float a0 = 0.f, a1 = 0.f, a2 = 0.f, b0 = 0.f, b1 = 0.f, b2 = 0.f;
#pragma unroll
    for (int p = 0; p < 4; p++) {
      int px = lane * 4 + p;
      float fa = (&va.x)[p], fb = (&vb.x)[p];
      if (px <= 85)  { a0 += fa; b0 += fb; }
      if (px >= 85 && px <= 170) { a1 += fa; b1 += fb; }
      if (px >= 170) { a2 += fa; b2 += fb; }
    }
#pragma unroll
    for (int off = 32; off >= 1; off >>= 1) {
      a0 += __shfl_xor(a0, off); a1 += __shfl_xor(a1, off); a2 += __shfl_xor(a2, off);
      b0 += __shfl_xor(b0, off); b1 += __shfl_xor(b1, off); b2 += __shfl_xor(b2, off);
    }
    if (lane == 0) {
      float* qa = rs1 + ((size_t)(b * 8 + 2 * cp) * 256 + row) * 3;
      qa[0] = a0; qa[1] = a1; qa[2] = a2;
      float* qb = qa + 768;
      qb[0] = b0; qb[1] = b1; qb[2] = b2;
    }
  } else {
    int u2 = u - 2048;
    int b = u2 >> 6, rg = u2 & 63;
    int row = rg * 4 + wave;
    int x0 = lane * 4;
    const float* hp = hist + (size_t)b * 8 * HWPX + row * HDIM + x0;
    float4 hv[8];
#pragma unroll
    for (int r = 0; r < 8; r++) hv[r] = *(const float4*)(hp + (size_t)r * HWPX);
    uchar4 rg4;
#pragma unroll
    for (int p = 0; p < 4; p++) {
      float best = (&hv[0].x)[p];
      int reg = 0;
#pragma unroll
      for (int r = 1; r < 8; r++) {
        float q = (&hv[r].x)[p];
        if (q > best) { best = q; reg = r; }   // strict > == JAX first-max
      }
      (&rg4.x)[p] = (unsigned char)reg;
    }
    *(uchar4*)(regmap + (size_t)b * HWPX + row * HDIM + x0) = rg4;
  }
}

// ---------------- P3 unit: rowsum over fp16 pair planes ---------------------
__device__ __forceinline__ void rowsum_unit(int u, int t,
                                            const uint* __restrict__ yh,
                                            float* __restrict__ rs) {
  int wave = t >> 6, lane = t & 63;
  int cp = u & 3, rg = (u >> 2) & 63, b = u >> 8;
  int row = rg * 4 + wave;
  uint4 uu = *(const uint4*)(yh + (size_t)(b * 4 + cp) * HWPX + row * HDIM + lane * 4);
  float a0 = 0.f, a1 = 0.f, a2 = 0.f, b0 = 0.f, b1 = 0.f, b2 = 0.f;
#pragma unroll
  for (int p = 0; p < 4; p++) {
    UH w; w.u = (&uu.x)[p];
    float fa = (float)w.h[0], fb = (float)w.h[1];
    int px = lane * 4 + p;
    if (px <= 85)  { a0 += fa; b0 += fb; }
    if (px >= 85 && px <= 170) { a1 += fa; b1 += fb; }
    if (px >= 170) { a2 += fa; b2 += fb; }
  }
#pragma unroll
  for (int off = 32; off >= 1; off >>= 1) {
    a0 += __shfl_xor(a0, off); a1 += __shfl_xor(a1, off); a2 += __shfl_xor(a2, off);
    b0 += __shfl_xor(b0, off); b1 += __shfl_xor(b1, off); b2 += __shfl_xor(b2, off);
  }
  if (lane == 0) {
    float* qa = rs + ((size_t)(b * 8 + 2 * cp) * 256 + row) * 3;
    qa[0] = a0; qa[1] = a1; qa[2] = a2;
    float* qb = qa + 768;
    qb[0] = b0; qb[1] = b1; qb[2] = b2;
  }
}

// ---------------- conv phase: inline buildK + conv + BN/ReLU, 4 px/thread ---
template <int LAYER>
__device__ __forceinline__ void conv_phase(
    ConvSmem& sm, int bid, int t,
    const uint* __restrict__ xh, const unsigned char* __restrict__ regmap,
    const float* __restrict__ rs,
    const float* __restrict__ wa, const float* __restrict__ ba,
    const float* __restrict__ wb, const float* __restrict__ bb,
    const float* __restrict__ g, const float* __restrict__ be,
    const float* __restrict__ m, const float* __restrict__ v,
    uint* __restrict__ outh, float* __restrict__ outf) {
  int b = bid & 7;                     // batch-per-XCD
  int rg = bid >> 3;                   // 0..63
  int wave = t >> 6, lane = t & 63;
  int row = rg * 4 + wave;
  int x0 = lane * 4;

  // ---- inline buildK: pool from rowsums ----
  if (t < 216) {
    int u = t / 3, part = t - 3 * (t / 3);
    int c = u / 9, ij = u % 9, i = ij / 3, j = ij % 3;
    int r0 = 85 * i + part * 29;
    int cnt = (part == 2) ? 28 : 29;
    const float* q = rs + ((size_t)(b * 8 + c) * 256 + r0) * 3 + j;
    float s = 0.f;
    for (int k = 0; k < cnt; k++) s += q[k * 3];
    sm.pp[u][part] = s;
  }
  if (t >= 248) {
    int oc = t - 248;
    float s = g[oc] * rsqrtf(v[oc] + 1e-5f);
    sm.bns[oc] = s;
    sm.bnsh[oc] = be[oc] - m[oc] * s;
  }
  __syncthreads();
  if (t < 72) sm.pP[t / 9][t % 9] = (sm.pp[t][0] + sm.pp[t][1] + sm.pp[t][2]) * (1.f / 7396.f);
  __syncthreads();
  for (int u = t; u < 576; u += 256) {
    int o = u / 9, ij = u - o * 9;
    float z = ba[o];
#pragma unroll
    for (int c = 0; c < 8; c++) z += sm.pP[c][ij] * wa[o * 8 + c];
    sm.hh[u] = 1.f / (1.f + expf(-z));
  }
  __syncthreads();
  // K: thread t owns dword-column (reg, oc, cipair q) across all 9 taps
  {
    int reg = t >> 5, z = t & 31, oc = z >> 2, q = z & 3;
    int row0 = reg * 64 + oc * 8 + q * 2;
    const float* w0p = wb + row0 * 8;
    float4 wA  = *(const float4*)(w0p);
    float4 wA2 = *(const float4*)(w0p + 4);
    float4 wB  = *(const float4*)(w0p + 8);
    float4 wB2 = *(const float4*)(w0p + 12);
    float bb0 = bb[row0], bb1 = bb[row0 + 1];
    const float* hp = sm.hh + reg * 72;
#pragma unroll
    for (int tap = 0; tap < 9; tap++) {
      float v0 = bb0, v1 = bb1;
#pragma unroll
      for (int cc = 0; cc < 4; cc++) {
        float hv = hp[cc * 9 + tap];
        v0 += hv * (&wA.x)[cc];
        v1 += hv * (&wB.x)[cc];
      }
#pragma unroll
      for (int cc = 0; cc < 4; cc++) {
        float hv = hp[(4 + cc) * 9 + tap];
        v0 += hv * (&wA2.x)[cc];
        v1 += hv * (&wB2.x)[cc];
      }
      UH pk;
      pk.h[0] = (__fp16)v0;
      pk.h[1] = (__fp16)v1;
      sm.KsU[reg * 292 + tap * 32 + z] = pk.u;
    }
  }
  __syncthreads();

  // ---- conv main: load window win[cpair][dy][6] as uints (h2 each) ----
  uint win[4][3][6];
#pragma unroll
  for (int cp = 0; cp < 4; cp++) {
    const uint* plane = xh + (size_t)(b * 4 + cp) * HWPX;
#pragma unroll
    for (int dy = 0; dy < 3; dy++) {
      int yy = row + dy - 1;
      if ((unsigned)yy < 256u) {
        const uint* rp = plane + yy * HDIM + x0;
        uint4 mv = *(const uint4*)rp;
        win[cp][dy][0] = (x0 > 0) ? rp[-1] : 0u;
        win[cp][dy][1] = mv.x; win[cp][dy][2] = mv.y;
        win[cp][dy][3] = mv.z; win[cp][dy][4] = mv.w;
        win[cp][dy][5] = (x0 < 252) ? rp[4] : 0u;
      } else {
#pragma unroll
        for (int q = 0; q < 6; q++) win[cp][dy][q] = 0u;
      }
    }
  }

  uchar4 rg4 = *(const uchar4*)(regmap + (size_t)b * HWPX + row * HDIM + x0);

  float acc[4][8];
#pragma unroll
  for (int p = 0; p < 4; p++)
#pragma unroll
    for (int oc = 0; oc < 8; oc++) acc[p][oc] = 0.f;

#pragma unroll
  for (int p = 0; p < 4; p++) {
    int reg = (&rg4.x)[p];
    const char* Kr = (const char*)sm.KsU + reg * 1168;
#pragma unroll
    for (int di = 0; di < 3; di++) {
#pragma unroll
      for (int dj = 0; dj < 3; dj++) {
        UH w0, w1, w2, w3;
        w0.u = win[0][di][p + dj];
        w1.u = win[1][di][p + dj];
        w2.u = win[2][di][p + dj];
        w3.u = win[3][di][p + dj];
        const char* kt = Kr + (di * 3 + dj) * 128;
#pragma unroll
        for (int oc = 0; oc < 8; oc++) {
          U4H kw;
          kw.u4 = *(const uint4*)(kt + oc * 16);
          float a = acc[p][oc];
          a = fdot2(w0.h, kw.h[0], a);
          a = fdot2(w1.h, kw.h[1], a);
          a = fdot2(w2.h, kw.h[2], a);
          a = fdot2(w3.h, kw.h[3], a);
          acc[p][oc] = a;
        }
      }
    }
  }

#pragma unroll
  for (int p = 0; p < 4; p++)
#pragma unroll
    for (int oc = 0; oc < 8; oc++)
      acc[p][oc] = fmaxf(acc[p][oc] * sm.bns[oc] + sm.bnsh[oc], 0.f);

  if (LAYER == 1) {
#pragma unroll
    for (int cp = 0; cp < 4; cp++) {
      U4H pk;
#pragma unroll
      for (int p = 0; p < 4; p++)
        pk.h[p] = __builtin_amdgcn_cvt_pkrtz(acc[p][2 * cp], acc[p][2 * cp + 1]);
      *(uint4*)(outh + (size_t)(b * 4 + cp) * HWPX + row * HDIM + x0) = pk.u4;
    }
  } else {
#pragma unroll
    for (int oc = 0; oc < 8; oc++) {
      float4 o4 = make_float4(acc[0][oc], acc[1][oc], acc[2][oc], acc[3][oc]);
      *(float4*)(outf + (size_t)(b * 8 + oc) * HWPX + row * HDIM + x0) = o4;
    }
  }
}

// ---------------- single cooperative kernel (grid 512) ----------------------
__global__ __launch_bounds__(256, 2) void fused_kernel(
    const float* __restrict__ x, const float* __restrict__ hist,
    const float* __restrict__ w1a, const float* __restrict__ b1a,
    const float* __restrict__ w1b, const float* __restrict__ b1b,
    const float* __restrict__ g1, const float* __restrict__ be1,
    const float* __restrict__ m1, const float* __restrict__ v1,
    const float* __restrict__ w2a, const float* __restrict__ b2a,
    const float* __restrict__ w2b, const float* __restrict__ b2b,
    const float* __restrict__ g2, const float* __restrict__ be2,
    const float* __restrict__ m2, const float* __restrict__ v2,
    float* __restrict__ outp, unsigned char* __restrict__ regmap,
    uint* __restrict__ xh, uint* __restrict__ y1h,
    float* __restrict__ rs1, float* __restrict__ rs2) {
  __shared__ ConvSmem sm;
  cg::grid_group grid = cg::this_grid();
  int bid = blockIdx.x;
  int t = threadIdx.x;

  for (int u = bid; u < 2560; u += 512) prep_unit(u, t, x, hist, rs1, xh, regmap);
  grid.sync();
  conv_phase<1>(sm, bid, t, xh, regmap, rs1, w1a, b1a, w1b, b1b,
                g1, be1, m1, v1, y1h, nullptr);
  grid.sync();
  for (int u = bid; u < 2048; u += 512) rowsum_unit(u, t, y1h, rs2);
  grid.sync();
  conv_phase<2>(sm, bid, t, y1h, regmap, rs2, w2a, b2a, w2b, b2b,
                g2, be2, m2, v2, nullptr, outp);
}

// ---------------- fallback standalone kernels (R6 path) ---------------------
__global__ __launch_bounds__(256) void prep_kernel(const float* __restrict__ x,
                                                   const float* __restrict__ hist,
                                                   float* __restrict__ rs,
                                                   uint* __restrict__ xh,
                                                   unsigned char* __restrict__ regmap) {
  prep_unit(blockIdx.x, threadIdx.x, x, hist, rs, xh, regmap);
}

__global__ __launch_bounds__(256) void rowsum_h_kernel(const uint* __restrict__ yh,
                                                       float* __restrict__ rs) {
  rowsum_unit(blockIdx.x, threadIdx.x, yh, rs);
}

template <int LAYER>
__global__ __launch_bounds__(256) void conv_kernel(
    const uint* __restrict__ xh, const unsigned char* __restrict__ regmap,
    const float* __restrict__ rs,
    const float* __restrict__ wa, const float* __restrict__ ba,
    const float* __restrict__ wb, const float* __restrict__ bb,
    const float* __restrict__ g, const float* __restrict__ be,
    const float* __restrict__ m, const float* __restrict__ v,
    uint* __restrict__ outh, float* __restrict__ outf) {
  __shared__ ConvSmem sm;
  conv_phase<LAYER>(sm, blockIdx.x, threadIdx.x, xh, regmap, rs,
                    wa, ba, wb, bb, g, be, m, v, outh, outf);
}

extern "C" void kernel_launch(void* const* d_in, const int* in_sizes, int n_in,
                              void* d_out, int out_size, void* d_ws, size_t ws_size,
                              hipStream_t stream) {
  const float* x    = (const float*)d_in[0];
  const float* hist = (const float*)d_in[1];
  const float* w1a  = (const float*)d_in[2];
  const float* b1a  = (const float*)d_in[3];
  const float* w1b  = (const float*)d_in[4];
  const float* b1b  = (const float*)d_in[5];
  const float* g1   = (const float*)d_in[6];
  const float* be1  = (const float*)d_in[7];
  const float* m1   = (const float*)d_in[8];
  const float* v1   = (const float*)d_in[9];
  const float* w2a  = (const float*)d_in[10];
  const float* b2a  = (const float*)d_in[11];
  const float* w2b  = (const float*)d_in[12];
  const float* b2b  = (const float*)d_in[13];
  const float* g2   = (const float*)d_in[14];
  const float* be2  = (const float*)d_in[15];
  const float* m2   = (const float*)d_in[16];
  const float* v2   = (const float*)d_in[17];
  float* outp = (float*)d_out;

  char* ws = (char*)d_ws;
  unsigned char* regmap = (unsigned char*)ws;            // 524288
  uint* xh  = (uint*)(ws + 524288);                      // 8388608
  uint* y1h = (uint*)(ws + 8912896);                     // 8388608
  float* rs1 = (float*)(ws + 17301504);                  // 98304
  float* rs2 = (float*)(ws + 17399808);                  // 98304

  void* args[] = {
    (void*)&x, (void*)&hist,
    (void*)&w1a, (void*)&b1a, (void*)&w1b, (void*)&b1b,
    (void*)&g1, (void*)&be1, (void*)&m1, (void*)&v1,
    (void*)&w2a, (void*)&b2a, (void*)&w2b, (void*)&b2b,
    (void*)&g2, (void*)&be2, (void*)&m2, (void*)&v2,
    (void*)&outp, (void*)&regmap, (void*)&xh, (void*)&y1h,
    (void*)&rs1, (void*)&rs2,
  };
  hipError_t err = hipLaunchCooperativeKernel((const void*)fused_kernel,
                                              dim3(512), dim3(256), args, 0, stream);
  if (err != hipSuccess) {
    (void)hipGetLastError();   // clear sticky error, then fallback (R6 path)
    prep_kernel<<<2560, 256, 0, stream>>>(x, hist, rs1, xh, regmap);
    conv_kernel<1><<<512, 256, 0, stream>>>(xh, regmap, rs1, w1a, b1a, w1b, b1b,
                                            g1, be1, m1, v1, y1h, nullptr);
    rowsum_h_kernel<<<2048, 256, 0, stream>>>(y1h, rs2);
    conv_kernel<2><<<512, 256, 0, stream>>>(y1h, regmap, rs2, w2a, b2a, w2b, b2b,
                                            g2, be2, m2, v2, nullptr, outp);
  }
}

// Round 9
// 55.720 us; speedup vs baseline: 4.2850x; 4.2850x over previous
//
#include <hip/hip_runtime.h>
#include <math.h>

// HistDRDoubleConv on gfx950 — 3 kernels (R6 structure, rowsum fused into conv1).
// B=8, Cin=Cmid=Cout=8, H=W=256, R=8. Pool windows at rows/cols {0,85,170}, k=86.
//  K1 prep:  rowsum(x)->rs1 ; xh = fp16 channel-pair planes ; regmap = argmax(hist)
//  K2 conv1: inline buildK1(rs1) -> conv(xh)+BN/ReLU -> y1h ; epilogue: rs2 from f32 acc
//  K3 conv2: inline buildK2(rs2) -> conv(y1h)+BN/ReLU -> out (f32)
// Conv: 4 px/thread, v_dot2_f32_f16 over ci-pairs; K in LDS, region stride
// 292 dwords so different-region lanes hit disjoint bank quads (conflict-free).

#define HWPX 65536
#define HDIM 256

typedef __fp16 h2 __attribute__((ext_vector_type(2)));

#if defined(__has_builtin) && __has_builtin(__builtin_amdgcn_fdot2)
__device__ __forceinline__ float fdot2(h2 a, h2 b, float c) {
  return __builtin_amdgcn_fdot2(a, b, c, false);
}
#else
__device__ __forceinline__ float fdot2(h2 a, h2 b, float c) {
  return c + (float)a[0] * (float)b[0] + (float)a[1] * (float)b[1];
}
#endif

union UH { uint u; h2 h; };
union U4H { uint4 u4; h2 h[4]; };

// ---------------- prep: rowsums + fp16 pair planes + regmap -----------------
__global__ __launch_bounds__(256) void prep_kernel(const float* __restrict__ x,
                                                   const float* __restrict__ hist,
                                                   float* __restrict__ rs1,
                                                   uint* __restrict__ xh,
                                                   unsigned char* __restrict__ regmap) {
  int u = blockIdx.x;
  int t = threadIdx.x;
  int wave = t >> 6, lane = t & 63;
  if (u < 2048) {
    int cp = u & 3, rg = (u >> 2) & 63, b = u >> 8;
    int row = rg * 4 + wave;
    const float* pa = x + ((size_t)(b * 8 + 2 * cp) * HWPX) + row * HDIM + lane * 4;
    const float4 va = *(const float4*)pa;
    const float4 vb = *(const float4*)(pa + HWPX);
    U4H pk;
    pk.h[0] = __builtin_amdgcn_cvt_pkrtz(va.x, vb.x);
    pk.h[1] = __builtin_amdgcn_cvt_pkrtz(va.y, vb.y);
    pk.h[2] = __builtin_amdgcn_cvt_pkrtz(va.z, vb.z);
    pk.h[3] = __builtin_amdgcn_cvt_pkrtz(va.w, vb.w);
    *(uint4*)(xh + (size_t)(b * 4 + cp) * HWPX + row * HDIM + lane * 4) = pk.u4;
    float a0 = 0.f, a1 = 0.f, a2 = 0.f, b0 = 0.f, b1 = 0.f, b2 = 0.f;
#pragma unroll
    for (int p = 0; p < 4; p++) {
      int px = lane * 4 + p;
      float fa = (&va.x)[p], fb = (&vb.x)[p];
      if (px <= 85)  { a0 += fa; b0 += fb; }
      if (px >= 85 && px <= 170) { a1 += fa; b1 += fb; }
      if (px >= 170) { a2 += fa; b2 += fb; }
    }
#pragma unroll
    for (int off = 32; off >= 1; off >>= 1) {
      a0 += __shfl_xor(a0, off); a1 += __shfl_xor(a1, off); a2 += __shfl_xor(a2, off);
      b0 += __shfl_xor(b0, off); b1 += __shfl_xor(b1, off); b2 += __shfl_xor(b2, off);
    }
    if (lane == 0) {
      float* qa = rs1 + ((size_t)(b * 8 + 2 * cp) * 256 + row) * 3;
      qa[0] = a0; qa[1] = a1; qa[2] = a2;
      float* qb = qa + 768;
      qb[0] = b0; qb[1] = b1; qb[2] = b2;
    }
  } else {
    int u2 = u - 2048;
    int b = u2 >> 6, rg = u2 & 63;
    int row = rg * 4 + wave;
    int x0 = lane * 4;
    const float* hp = hist + (size_t)b * 8 * HWPX + row * HDIM + x0;
    float4 hv[8];
#pragma unroll
    for (int r = 0; r < 8; r++) hv[r] = *(const float4*)(hp + (size_t)r * HWPX);
    uchar4 rg4;
#pragma unroll
    for (int p = 0; p < 4; p++) {
      float best = (&hv[0].x)[p];
      int reg = 0;
#pragma unroll
      for (int r = 1; r < 8; r++) {
        float q = (&hv[r].x)[p];
        if (q > best) { best = q; reg = r; }   // strict > == JAX first-max
      }
      (&rg4.x)[p] = (unsigned char)reg;
    }
    *(uchar4*)(regmap + (size_t)b * HWPX + row * HDIM + x0) = rg4;
  }
}

// ---------------- conv + BN + ReLU, inline buildK, 4 px/thread --------------
// LAYER 1: out -> fp16 pair planes (y1h) + fused rowsum epilogue -> rs2.
// LAYER 2: out -> f32.
template <int LAYER>
__global__ __launch_bounds__(256) void conv_kernel(
    const uint* __restrict__ xh, const unsigned char* __restrict__ regmap,
    const float* __restrict__ rs,
    const float* __restrict__ wa, const float* __restrict__ ba,
    const float* __restrict__ wb, const float* __restrict__ bb,
    const float* __restrict__ g, const float* __restrict__ be,
    const float* __restrict__ m, const float* __restrict__ v,
    uint* __restrict__ outh, float* __restrict__ outf,
    float* __restrict__ rs2out) {
  __shared__ uint KsU[8 * 292];        // 9344 B
  __shared__ float pp[72][3];
  __shared__ float pP[8][9];
  __shared__ float hh[576];
  __shared__ float bns[8], bnsh[8];

  int bid = blockIdx.x;
  int b = bid & 7;                     // batch-per-XCD
  int rg = bid >> 3;                   // 0..63
  int wave = threadIdx.x >> 6, lane = threadIdx.x & 63;
  int row = rg * 4 + wave;
  int x0 = lane * 4;
  int t = threadIdx.x;

  // ---- inline buildK: pool from rowsums ----
  if (t < 216) {
    int u = t / 3, part = t - 3 * (t / 3);
    int c = u / 9, ij = u % 9, i = ij / 3, j = ij % 3;
    int r0 = 85 * i + part * 29;
    int cnt = (part == 2) ? 28 : 29;
    const float* q = rs + ((size_t)(b * 8 + c) * 256 + r0) * 3 + j;
    float s = 0.f;
    for (int k = 0; k < cnt; k++) s += q[k * 3];
    pp[u][part] = s;
  }
  if (t >= 248) {
    int oc = t - 248;
    float s = g[oc] * rsqrtf(v[oc] + 1e-5f);
    bns[oc] = s;
    bnsh[oc] = be[oc] - m[oc] * s;
  }
  __syncthreads();
  if (t < 72) pP[t / 9][t % 9] = (pp[t][0] + pp[t][1] + pp[t][2]) * (1.f / 7396.f);
  __syncthreads();
  for (int u = t; u < 576; u += 256) {
    int o = u / 9, ij = u - o * 9;
    float z = ba[o];
#pragma unroll
    for (int c = 0; c < 8; c++) z += pP[c][ij] * wa[o * 8 + c];
    hh[u] = 1.f / (1.f + expf(-z));
  }
  __syncthreads();
  // K: thread t owns dword-column (reg, oc, cipair q) across all 9 taps
  {
    int reg = t >> 5, z = t & 31, oc = z >> 2, q = z & 3;
    int row0 = reg * 64 + oc * 8 + q * 2;
    const float* w0p = wb + row0 * 8;
    float4 wA  = *(const float4*)(w0p);
    float4 wA2 = *(const float4*)(w0p + 4);
    float4 wB  = *(const float4*)(w0p + 8);
    float4 wB2 = *(const float4*)(w0p + 12);
    float bb0 = bb[row0], bb1 = bb[row0 + 1];
    const float* hp = hh + reg * 72;
#pragma unroll
    for (int tap = 0; tap < 9; tap++) {
      float v0 = bb0, v1 = bb1;
#pragma unroll
      for (int cc = 0; cc < 4; cc++) {
        float hv = hp[cc * 9 + tap];
        v0 += hv * (&wA.x)[cc];
        v1 += hv * (&wB.x)[cc];
      }
#pragma unroll
      for (int cc = 0; cc < 4; cc++) {
        float hv = hp[(4 + cc) * 9 + tap];
        v0 += hv * (&wA2.x)[cc];
        v1 += hv * (&wB2.x)[cc];
      }
      UH pk;
      pk.h[0] = (__fp16)v0;
      pk.h[1] = (__fp16)v1;
      KsU[reg * 292 + tap * 32 + z] = pk.u;
    }
  }
  __syncthreads();

  // ---- conv main: load window win[cpair][dy][6] as uints (h2 each) ----
  uint win[4][3][6];
#pragma unroll
  for (int cp = 0; cp < 4; cp++) {
    const uint* plane = xh + (size_t)(b * 4 + cp) * HWPX;
#pragma unroll
    for (int dy = 0; dy < 3; dy++) {
      int yy = row + dy - 1;
      if ((unsigned)yy < 256u) {
        const uint* rp = plane + yy * HDIM + x0;
        uint4 mv = *(const uint4*)rp;
        win[cp][dy][0] = (x0 > 0) ? rp[-1] : 0u;
        win[cp][dy][1] = mv.x; win[cp][dy][2] = mv.y;
        win[cp][dy][3] = mv.z; win[cp][dy][4] = mv.w;
        win[cp][dy][5] = (x0 < 252) ? rp[4] : 0u;
      } else {
#pragma unroll
        for (int q = 0; q < 6; q++) win[cp][dy][q] = 0u;
      }
    }
  }

  uchar4 rg4 = *(const uchar4*)(regmap + (size_t)b * HWPX + row * HDIM + x0);

  float acc[4][8];
#pragma unroll
  for (int p = 0; p < 4; p++)
#pragma unroll
    for (int oc = 0; oc < 8; oc++) acc[p][oc] = 0.f;

#pragma unroll
  for (int p = 0; p < 4; p++) {
    int reg = (&rg4.x)[p];
    const char* Kr = (const char*)KsU + reg * 1168;
#pragma unroll
    for (int di = 0; di < 3; di++) {
#pragma unroll
      for (int dj = 0; dj < 3; dj++) {
        UH w0, w1, w2, w3;
        w0.u = win[0][di][p + dj];
        w1.u = win[1][di][p + dj];
        w2.u = win[2][di][p + dj];
        w3.u = win[3][di][p + dj];
        const char* kt = Kr + (di * 3 + dj) * 128;
#pragma unroll
        for (int oc = 0; oc < 8; oc++) {
          U4H kw;
          kw.u4 = *(const uint4*)(kt + oc * 16);
          float a = acc[p][oc];
          a = fdot2(w0.h, kw.h[0], a);
          a = fdot2(w1.h, kw.h[1], a);
          a = fdot2(w2.h, kw.h[2], a);
          a = fdot2(w3.h, kw.h[3], a);
          acc[p][oc] = a;
        }
      }
    }
  }

  // BN + ReLU
#pragma unroll
  for (int p = 0; p < 4; p++)
#pragma unroll
    for (int oc = 0; oc < 8; oc++)
      acc[p][oc] = fmaxf(acc[p][oc] * bns[oc] + bnsh[oc], 0.f);

  if (LAYER == 1) {
#pragma unroll
    for (int cp = 0; cp < 4; cp++) {
      U4H pk;
#pragma unroll
      for (int p = 0; p < 4; p++)
        pk.h[p] = __builtin_amdgcn_cvt_pkrtz(acc[p][2 * cp], acc[p][2 * cp + 1]);
      *(uint4*)(outh + (size_t)(b * 4 + cp) * HWPX + row * HDIM + x0) = pk.u4;
    }
    // ---- fused rowsum epilogue: rs2 for layer-2 pool (f32 acc, per-wave row)
#pragma unroll
    for (int oc = 0; oc < 8; oc++) {
      float s0 = 0.f, s1 = 0.f, s2 = 0.f;
#pragma unroll
      for (int p = 0; p < 4; p++) {
        int px = x0 + p;
        float val = acc[p][oc];
        if (px <= 85) s0 += val;
        if (px >= 85 && px <= 170) s1 += val;
        if (px >= 170) s2 += val;
      }
#pragma unroll
      for (int off = 32; off >= 1; off >>= 1) {
        s0 += __shfl_xor(s0, off);
        s1 += __shfl_xor(s1, off);
        s2 += __shfl_xor(s2, off);
      }
      if (lane == 0) {
        float* q = rs2out + ((size_t)(b * 8 + oc) * 256 + row) * 3;
        q[0] = s0; q[1] = s1; q[2] = s2;
      }
    }
  } else {
#pragma unroll
    for (int oc = 0; oc < 8; oc++) {
      float4 o4 = make_float4(acc[0][oc], acc[1][oc], acc[2][oc], acc[3][oc]);
      *(float4*)(outf + (size_t)(b * 8 + oc) * HWPX + row * HDIM + x0) = o4;
    }
  }
}

extern "C" void kernel_launch(void* const* d_in, const int* in_sizes, int n_in,
                              void* d_out, int out_size, void* d_ws, size_t ws_size,
                              hipStream_t stream) {
  const float* x    = (const float*)d_in[0];
  const float* hist = (const float*)d_in[1];
  const float* w1a  = (const float*)d_in[2];
  const float* b1a  = (const float*)d_in[3];
  const float* w1b  = (const float*)d_in[4];
  const float* b1b  = (const float*)d_in[5];
  const float* g1   = (const float*)d_in[6];
  const float* be1  = (const float*)d_in[7];
  const float* m1   = (const float*)d_in[8];
  const float* v1   = (const float*)d_in[9];
  const float* w2a  = (const float*)d_in[10];
  const float* b2a  = (const float*)d_in[11];
  const float* w2b  = (const float*)d_in[12];
  const float* b2b  = (const float*)d_in[13];
  const float* g2   = (const float*)d_in[14];
  const float* be2  = (const float*)d_in[15];
  const float* m2   = (const float*)d_in[16];
  const float* v2   = (const float*)d_in[17];
  float* outp = (float*)d_out;

  char* ws = (char*)d_ws;
  unsigned char* regmap = (unsigned char*)ws;            // 524288
  uint* xh  = (uint*)(ws + 524288);                      // 8388608
  uint* y1h = (uint*)(ws + 8912896);                     // 8388608
  float* rs1 = (float*)(ws + 17301504);                  // 98304
  float* rs2 = (float*)(ws + 17399808);                  // 98304

  prep_kernel<<<2560, 256, 0, stream>>>(x, hist, rs1, xh, regmap);
  conv_kernel<1><<<512, 256, 0, stream>>>(xh, regmap, rs1, w1a, b1a, w1b, b1b,
                                          g1, be1, m1, v1, y1h, nullptr, rs2);
  conv_kernel<2><<<512, 256, 0, stream>>>(y1h, regmap, rs2, w2a, b2a, w2b, b2b,
                                          g2, be2, m2, v2, nullptr, outp, nullptr);
}